// Round 8
// baseline (95.433 us; speedup 1.0000x reference)
//
#include <hip/hip_runtime.h>
#include <math.h>

#define NG 9
#define NBLK 1024          // pair blocks: 4/CU
#define CHROWS 256         // classification chunk rows
#define NCHMAX 256         // supports B <= 65536
#define JT 32              // j-tile width (nbI*nbJ = 8*128 = 1024 at B=8192)
#define ITILE 512          // i-fragment: 2 slots x 256 threads (packed f32x2)
#define LOG2E 1.4426950408889634f
#define LN2   0.6931471805599453f

typedef float f32x2 __attribute__((ext_vector_type(2)));

// ---------------------------------------------------------------------------
// Dispatch 1: classify all rows exactly once (32 blocks). Per-chunk compaction
// into deterministic segments + plain-stored per-chunk counts: nothing needs
// zeroing, no atomics. Block 0 also zeroes the completion ticket (visible to
// the next dispatch via the kernel boundary).
// ---------------------------------------------------------------------------
__global__ __launch_bounds__(256) void k_classify(
    const float* __restrict__ logits, const float* __restrict__ ytox,
    const float* __restrict__ yid, int B,
    int* __restrict__ cntT, int* __restrict__ cntN,
    int* __restrict__ gTc, int* __restrict__ gNc,
    float2* __restrict__ iTmp, float2* __restrict__ jTmp,
    int* __restrict__ ticket) {

    __shared__ int wT[4], wN[4], oT[4], oN[4];
    __shared__ int gT[4][NG], gN[4][NG];

    const int tid = threadIdx.x, lane = tid & 63, wave = tid >> 6;
    const int c = blockIdx.x;
    const int row = c * CHROWS + tid;
    const bool v = row < B;

    if (c == 0 && tid == 0) ticket[0] = 0;   // reset completion counter

    float l = 0.f; bool tox = false, non = false; int m = 0;
    if (v) {
        l = logits[row] * LOG2E;          // pre-scale: softplus in log2 domain
        tox = ytox[row] >= 0.5f;
        non = !tox;
#pragma unroll
        for (int g = 0; g < NG; ++g)
            if (yid[row * NG + g] >= 0.5f) m |= 1 << g;
    }
    const unsigned long long bTox = __ballot(tox), bNon = __ballot(non);
    const unsigned long long lt = (1ull << lane) - 1ull;
    const int pT = __popcll(bTox & lt), pN = __popcll(bNon & lt);
    if (lane == 0) { wT[wave] = __popcll(bTox); wN[wave] = __popcll(bNon); }
#pragma unroll
    for (int g = 0; g < NG; ++g) {
        const unsigned long long bt = __ballot(tox && ((m >> g) & 1));
        const unsigned long long bn = __ballot(non && ((m >> g) & 1));
        if (lane == 0) { gT[wave][g] = __popcll(bt); gN[wave][g] = __popcll(bn); }
    }
    __syncthreads();
    if (tid == 0) {
        int a = 0, b = 0;
#pragma unroll
        for (int w = 0; w < 4; ++w) { oT[w] = a; a += wT[w]; oN[w] = b; b += wN[w]; }
        cntT[c] = a; cntN[c] = b;
    }
    __syncthreads();
    if (tox) iTmp[c * CHROWS + oT[wave] + pT] = make_float2(l, __int_as_float(m));
    if (non) jTmp[c * CHROWS + oN[wave] + pN] = make_float2(l, __int_as_float(m));
    if (tid < NG)
        gTc[c * NG + tid] = gT[0][tid] + gT[1][tid] + gT[2][tid] + gT[3][tid];
    else if (tid >= 64 && tid < 64 + NG) {
        const int g = tid - 64;
        gNc[c * NG + g] = gN[0][g] + gN[1][g] + gN[2][g] + gN[3][g];
    }
}

// ---------------------------------------------------------------------------
// Dispatch 2: pair kernel + fused finalize in the LAST block.
// Publishing: wave 0 stores the 27 partials as AGENT-scope atomic stores
// (write-through to the coherence point), then tid0 does an ACQ_REL ticket
// fetch_add in the SAME wave -> release (vmcnt wait) orders those stores.
// Last incrementer re-reads part[] with agent-scope loads in the exact same
// q-ascending order as the old k_final -> bit-identical reduction.
// ---------------------------------------------------------------------------
__global__ __launch_bounds__(256, 4) void k_pairs(
    const int* __restrict__ cntT, const int* __restrict__ cntN,
    const int* __restrict__ gTc, const int* __restrict__ gNc,
    const float2* __restrict__ iTmp, const float2* __restrict__ jTmp,
    int B, float* __restrict__ part, int* __restrict__ ticket,
    float* __restrict__ out) {

    __shared__ int offT[NCHMAX + 1], offN[NCHMAX + 1];
    __shared__ float2 jS[JT];
    __shared__ float red[4][27];
    __shared__ float acc[27];

    const int tid = threadIdx.x, lane = tid & 63, wave = tid >> 6;
    const int blk = blockIdx.x;
    const int nCh = (B + CHROWS - 1) / CHROWS;

    for (int c = tid; c < nCh; c += 256) { offT[c + 1] = cntT[c]; offN[c + 1] = cntN[c]; }
    if (tid == 0) { offT[0] = 0; offN[0] = 0; }
    if (tid < 27) acc[tid] = 0.f;
    __syncthreads();
    if (tid == 0)
        for (int c = 0; c < nCh; ++c) { offT[c + 1] += offT[c]; offN[c + 1] += offN[c]; }
    __syncthreads();
    const int nI = offT[nCh], nJ = offN[nCh];

    auto findChunk = [&](const int* off, int k) {     // dense idx -> chunk
        int lo = 0, hi = nCh;
        while (hi - lo > 1) { const int mid = (lo + hi) >> 1; if (off[mid] <= k) lo = mid; else hi = mid; }
        return lo;
    };

    f32x2 li = {1e30f, 1e30f};        // sentinel: exp2(-inf)=0 -> contributes 0
    int mi0 = 0, mi1 = 0;
    f32x2 Ra = {0.f, 0.f};
    f32x2 Rg[NG];
#pragma unroll
    for (int g = 0; g < NG; ++g) Rg[g] = (f32x2){0.f, 0.f};

    auto flush = [&]() {   // fold 2 packed slots x 9 groups into 27 block sums
#pragma unroll
        for (int g = 0; g < NG; ++g) {
            const bool i0 = (mi0 >> g) & 1, i1 = (mi1 >> g) & 1;
            const float r0 = Rg[g].x, r1 = Rg[g].y;
            float x0 = (i0 ? r0 : 0.f) + (i1 ? r1 : 0.f);
            float x1 = (i0 ? 0.f : r0) + (i1 ? 0.f : r1);
            float x2 = (i0 ? (Ra.x - r0) : 0.f) + (i1 ? (Ra.y - r1) : 0.f);
#pragma unroll
            for (int off = 32; off > 0; off >>= 1) {
                x0 += __shfl_xor(x0, off, 64);
                x1 += __shfl_xor(x1, off, 64);
                x2 += __shfl_xor(x2, off, 64);
            }
            if (lane == 0) {
                red[wave][g] = x0; red[wave][NG + g] = x1; red[wave][2 * NG + g] = x2;
            }
        }
        __syncthreads();
        if (tid < 27)
            acc[tid] += red[0][tid] + red[1][tid] + red[2][tid] + red[3][tid];
    };

    const int nbI = (nI + ITILE - 1) / ITILE;
    const int nbJ = (nJ + JT - 1) / JT;
    const int nT = nbI * nbJ;

    int prev_bi = -1;
    for (int t = blk; t < nT; t += NBLK) {
        const int bi = t % nbI, bj = t / nbI;   // j-major: bi stable per block
        if (bi != prev_bi) {
            if (prev_bi >= 0) flush();
            const int k0 = bi * ITILE + tid, k1 = k0 + 256;
            float2 a0 = make_float2(1e30f, 0.f), a1 = make_float2(1e30f, 0.f);
            if (k0 < nI) { const int c = findChunk(offT, k0); a0 = iTmp[c * CHROWS + (k0 - offT[c])]; }
            if (k1 < nI) { const int c = findChunk(offT, k1); a1 = iTmp[c * CHROWS + (k1 - offT[c])]; }
            li.x = a0.x; mi0 = __float_as_int(a0.y);
            li.y = a1.x; mi1 = __float_as_int(a1.y);
            Ra = (f32x2){0.f, 0.f};
#pragma unroll
            for (int g = 0; g < NG; ++g) Rg[g] = (f32x2){0.f, 0.f};
            prev_bi = bi;
        }
        const int jbeg = bj * JT;
        const int jcnt = min(JT, nJ - jbeg);
        __syncthreads();                         // jS reuse + red/acc ordering
        if (tid < jcnt) {
            const int k = jbeg + tid;
            const int c = findChunk(offN, k);
            jS[tid] = jTmp[c * CHROWS + (k - offN[c])];
        }
        __syncthreads();
#pragma unroll 2
        for (int k = 0; k < jcnt; ++k) {
            const float2 jv = jS[k];                                  // b64 broadcast
            const int mj = __builtin_amdgcn_readfirstlane(__float_as_int(jv.y));
            const f32x2 ljv = {jv.x, jv.x};
            const f32x2 d = ljv - li;
            f32x2 e;
            e.x = __builtin_amdgcn_exp2f(d.x);                        // trans x2
            e.y = __builtin_amdgcn_exp2f(d.y);
            const f32x2 one = {1.f, 1.f};
            const f32x2 tpe = e + one;                                // v_pk_add
            f32x2 s;
            s.x = __builtin_amdgcn_logf(tpe.x);                       // trans x2
            s.y = __builtin_amdgcn_logf(tpe.y);
            Ra = Ra + s;                                              // v_pk_add
#pragma unroll
            for (int g = 0; g < NG; ++g) {
                const float bg = ((mj >> g) & 1) ? 1.f : 0.f;          // SGPR select
                const f32x2 bgv = {bg, bg};
                Rg[g] = __builtin_elementwise_fma(bgv, s, Rg[g]);      // v_pk_fma
            }
        }
    }
    if (prev_bi >= 0) flush();

    // ---- publish (wave 0) + completion ticket (same wave => release works) ----
    if (tid < 27)
        __hip_atomic_store(&part[tid * NBLK + blk], acc[tid],
                           __ATOMIC_RELAXED, __HIP_MEMORY_SCOPE_AGENT);
    __shared__ int isLast;
    if (tid == 0) {
        const int old = __hip_atomic_fetch_add(ticket, 1, __ATOMIC_ACQ_REL,
                                               __HIP_MEMORY_SCOPE_AGENT);
        isLast = (old == NBLK - 1);
    }
    __syncthreads();
    if (!isLast) return;

    // ---- last block: reduce 27 rows (agent loads, fixed order) + fp64 tail ----
    __shared__ float fin[27];
    __shared__ int cTs[NG], cNs[NG], nTs, nNs;
    for (int r = wave; r < 27; r += 4) {
        float s = 0.f;
#pragma unroll
        for (int q = 0; q < NBLK / 64; ++q)
            s += __hip_atomic_load(&part[r * NBLK + (q << 6) + lane],
                                   __ATOMIC_RELAXED, __HIP_MEMORY_SCOPE_AGENT);
#pragma unroll
        for (int off = 32; off > 0; off >>= 1) s += __shfl_xor(s, off, 64);
        if (lane == 0) fin[r] = s * LN2;     // undo log2-domain accumulation
    }
    if (tid < NG) {
        int s = 0;
        for (int c = 0; c < nCh; ++c) s += gTc[c * NG + tid];
        cTs[tid] = s;
    } else if (tid >= 64 && tid < 64 + NG) {
        const int g = tid - 64;
        int s = 0;
        for (int c = 0; c < nCh; ++c) s += gNc[c * NG + g];
        cNs[g] = s;
    } else if (tid == 128) {
        nTs = nI;
    } else if (tid == 192) {
        nNs = nJ;
    }
    __syncthreads();
    if (tid == 0) {
        const long long nT64 = nTs, nN64 = nNs;
        double accd = 0.0; int ngv = 0;
        for (int g = 0; g < NG; ++g) {
            const long long cT = cTs[g], cN = cNs[g];
            const long long c0 = cT * cN;
            const long long c1 = (nT64 - cT) * cN;
            const long long c2 = cT * (nN64 - cN);
            const double t0 = (double)fin[g]          / (double)(c0 > 0 ? c0 : 1);
            const double t1 = (double)fin[NG + g]     / (double)(c1 > 0 ? c1 : 1);
            const double t2 = (double)fin[2 * NG + g] / (double)(c2 > 0 ? c2 : 1);
            const int nv = (c0 > 0) + (c1 > 0) + (c2 > 0);
            const double gl = ((c0 > 0 ? t0 : 0.0) + (c1 > 0 ? t1 : 0.0) +
                               (c2 > 0 ? t2 : 0.0)) / (double)(nv > 0 ? nv : 1);
            if (nv > 0) { const double g2 = gl * gl; accd += g2 * g2; ++ngv; }
        }
        const double mp = accd / (double)(ngv > 0 ? ngv : 1);
        const double loss = sqrt(sqrt(mp));  // ^(1/4)
        out[0] = (float)(ngv > 0 ? loss : 0.0);
    }
}

extern "C" void kernel_launch(void* const* d_in, const int* in_sizes, int n_in,
                              void* d_out, int out_size, void* d_ws, size_t ws_size,
                              hipStream_t stream) {
    const float* logits = (const float*)d_in[0];
    const float* ytox   = (const float*)d_in[1];
    const float* yid    = (const float*)d_in[2];
    const int B = in_sizes[0];
    const int nCh = (B + CHROWS - 1) / CHROWS;

    char* ws = (char*)d_ws;
    int* cntT = (int*)ws;                               // NCHMAX
    int* cntN = cntT + NCHMAX;                          // NCHMAX
    int* gTc  = cntN + NCHMAX;                          // NCHMAX*NG
    int* gNc  = gTc + NCHMAX * NG;                      // NCHMAX*NG
    int* ticket = gNc + NCHMAX * NG;                    // 1 (+31 pad)
    float2* iTmp = (float2*)(ticket + 32);              // B float2 (8B aligned)
    float2* jTmp = iTmp + B;                            // B float2
    float*  part = (float*)(jTmp + B);                  // 27*NBLK floats

    k_classify<<<dim3(nCh), dim3(256), 0, stream>>>(
        logits, ytox, yid, B, cntT, cntN, gTc, gNc, iTmp, jTmp, ticket);
    k_pairs<<<dim3(NBLK), dim3(256), 0, stream>>>(
        cntT, cntN, gTc, gNc, iTmp, jTmp, B, part, ticket, (float*)d_out);
}

// Round 9
// 89.841 us; speedup vs baseline: 1.0622x; 1.0622x over previous
//
#include <hip/hip_runtime.h>
#include <math.h>

#define NG 9
#define NBLK 1024          // pair blocks: 4/CU
#define CHROWS 256         // classification chunk rows
#define NCHMAX 256         // supports B <= 65536
#define JT 32              // j-tile width (nbI*nbJ = 8*128 = 1024 at B=8192)
#define ITILE 512          // i-fragment: 2 slots x 256 threads (packed f32x2)
#define LOG2E 1.4426950408889634f
#define LN2   0.6931471805599453f

typedef float f32x2 __attribute__((ext_vector_type(2)));

// ---------------------------------------------------------------------------
// Dispatch 1: classify all rows exactly once (32 blocks). Per-chunk compaction
// into deterministic segments + plain-stored per-chunk counts: no memset, no
// atomics, no inter-block traffic. (Proven in R6.)
// ---------------------------------------------------------------------------
__global__ __launch_bounds__(256) void k_classify(
    const float* __restrict__ logits, const float* __restrict__ ytox,
    const float* __restrict__ yid, int B,
    int* __restrict__ cntT, int* __restrict__ cntN,
    int* __restrict__ gTc, int* __restrict__ gNc,
    float2* __restrict__ iTmp, float2* __restrict__ jTmp) {

    __shared__ int wT[4], wN[4], oT[4], oN[4];
    __shared__ int gT[4][NG], gN[4][NG];

    const int tid = threadIdx.x, lane = tid & 63, wave = tid >> 6;
    const int c = blockIdx.x;
    const int row = c * CHROWS + tid;
    const bool v = row < B;

    float l = 0.f; bool tox = false, non = false; int m = 0;
    if (v) {
        l = logits[row] * LOG2E;          // pre-scale: softplus in log2 domain
        tox = ytox[row] >= 0.5f;
        non = !tox;
#pragma unroll
        for (int g = 0; g < NG; ++g)
            if (yid[row * NG + g] >= 0.5f) m |= 1 << g;
    }
    const unsigned long long bTox = __ballot(tox), bNon = __ballot(non);
    const unsigned long long lt = (1ull << lane) - 1ull;
    const int pT = __popcll(bTox & lt), pN = __popcll(bNon & lt);
    if (lane == 0) { wT[wave] = __popcll(bTox); wN[wave] = __popcll(bNon); }
#pragma unroll
    for (int g = 0; g < NG; ++g) {
        const unsigned long long bt = __ballot(tox && ((m >> g) & 1));
        const unsigned long long bn = __ballot(non && ((m >> g) & 1));
        if (lane == 0) { gT[wave][g] = __popcll(bt); gN[wave][g] = __popcll(bn); }
    }
    __syncthreads();
    if (tid == 0) {
        int a = 0, b = 0;
#pragma unroll
        for (int w = 0; w < 4; ++w) { oT[w] = a; a += wT[w]; oN[w] = b; b += wN[w]; }
        cntT[c] = a; cntN[c] = b;
    }
    __syncthreads();
    if (tox) iTmp[c * CHROWS + oT[wave] + pT] = make_float2(l, __int_as_float(m));
    if (non) jTmp[c * CHROWS + oN[wave] + pN] = make_float2(l, __int_as_float(m));
    if (tid < NG)
        gTc[c * NG + tid] = gT[0][tid] + gT[1][tid] + gT[2][tid] + gT[3][tid];
    else if (tid >= 64 && tid < 64 + NG) {
        const int g = tid - 64;
        gNc[c * NG + g] = gN[0][g] + gN[1][g] + gN[2][g] + gN[3][g];
    }
}

// ---------------------------------------------------------------------------
// Dispatch 2: pair kernel. LDS prefix table + binary-search indirection over
// the ragged per-chunk segments (proven R2/R6); packed-FP32 inner loop
// (proven R7). Plain partial stores; every slot written unconditionally.
// ---------------------------------------------------------------------------
__global__ __launch_bounds__(256, 4) void k_pairs(
    const int* __restrict__ cntT, const int* __restrict__ cntN,
    const float2* __restrict__ iTmp, const float2* __restrict__ jTmp,
    int B, float* __restrict__ part) {

    __shared__ int offT[NCHMAX + 1], offN[NCHMAX + 1];
    __shared__ float2 jS[JT];
    __shared__ float red[4][27];
    __shared__ float acc[27];

    const int tid = threadIdx.x, lane = tid & 63, wave = tid >> 6;
    const int blk = blockIdx.x;
    const int nCh = (B + CHROWS - 1) / CHROWS;

    for (int c = tid; c < nCh; c += 256) { offT[c + 1] = cntT[c]; offN[c + 1] = cntN[c]; }
    if (tid == 0) { offT[0] = 0; offN[0] = 0; }
    if (tid < 27) acc[tid] = 0.f;
    __syncthreads();
    if (tid == 0)
        for (int c = 0; c < nCh; ++c) { offT[c + 1] += offT[c]; offN[c + 1] += offN[c]; }
    __syncthreads();
    const int nI = offT[nCh], nJ = offN[nCh];

    auto findChunk = [&](const int* off, int k) {     // dense idx -> chunk
        int lo = 0, hi = nCh;
        while (hi - lo > 1) { const int mid = (lo + hi) >> 1; if (off[mid] <= k) lo = mid; else hi = mid; }
        return lo;
    };

    f32x2 li = {1e30f, 1e30f};        // sentinel: exp2(-inf)=0 -> contributes 0
    int mi0 = 0, mi1 = 0;
    f32x2 Ra = {0.f, 0.f};
    f32x2 Rg[NG];
#pragma unroll
    for (int g = 0; g < NG; ++g) Rg[g] = (f32x2){0.f, 0.f};

    auto flush = [&]() {   // fold 2 packed slots x 9 groups into 27 block sums
#pragma unroll
        for (int g = 0; g < NG; ++g) {
            const bool i0 = (mi0 >> g) & 1, i1 = (mi1 >> g) & 1;
            const float r0 = Rg[g].x, r1 = Rg[g].y;
            float x0 = (i0 ? r0 : 0.f) + (i1 ? r1 : 0.f);
            float x1 = (i0 ? 0.f : r0) + (i1 ? 0.f : r1);
            float x2 = (i0 ? (Ra.x - r0) : 0.f) + (i1 ? (Ra.y - r1) : 0.f);
#pragma unroll
            for (int off = 32; off > 0; off >>= 1) {
                x0 += __shfl_xor(x0, off, 64);
                x1 += __shfl_xor(x1, off, 64);
                x2 += __shfl_xor(x2, off, 64);
            }
            if (lane == 0) {
                red[wave][g] = x0; red[wave][NG + g] = x1; red[wave][2 * NG + g] = x2;
            }
        }
        __syncthreads();
        if (tid < 27)
            acc[tid] += red[0][tid] + red[1][tid] + red[2][tid] + red[3][tid];
    };

    const int nbI = (nI + ITILE - 1) / ITILE;
    const int nbJ = (nJ + JT - 1) / JT;
    const int nT = nbI * nbJ;

    int prev_bi = -1;
    for (int t = blk; t < nT; t += NBLK) {
        const int bi = t % nbI, bj = t / nbI;   // j-major: bi stable per block
        if (bi != prev_bi) {
            if (prev_bi >= 0) flush();
            const int k0 = bi * ITILE + tid, k1 = k0 + 256;
            float2 a0 = make_float2(1e30f, 0.f), a1 = make_float2(1e30f, 0.f);
            if (k0 < nI) { const int c = findChunk(offT, k0); a0 = iTmp[c * CHROWS + (k0 - offT[c])]; }
            if (k1 < nI) { const int c = findChunk(offT, k1); a1 = iTmp[c * CHROWS + (k1 - offT[c])]; }
            li.x = a0.x; mi0 = __float_as_int(a0.y);
            li.y = a1.x; mi1 = __float_as_int(a1.y);
            Ra = (f32x2){0.f, 0.f};
#pragma unroll
            for (int g = 0; g < NG; ++g) Rg[g] = (f32x2){0.f, 0.f};
            prev_bi = bi;
        }
        const int jbeg = bj * JT;
        const int jcnt = min(JT, nJ - jbeg);
        __syncthreads();                         // jS reuse + red/acc ordering
        if (tid < jcnt) {
            const int k = jbeg + tid;
            const int c = findChunk(offN, k);
            jS[tid] = jTmp[c * CHROWS + (k - offN[c])];
        }
        __syncthreads();
#pragma unroll 2
        for (int k = 0; k < jcnt; ++k) {
            const float2 jv = jS[k];                                  // b64 broadcast
            const int mj = __builtin_amdgcn_readfirstlane(__float_as_int(jv.y));
            const f32x2 ljv = {jv.x, jv.x};
            const f32x2 d = ljv - li;
            f32x2 e;
            e.x = __builtin_amdgcn_exp2f(d.x);                        // trans x2
            e.y = __builtin_amdgcn_exp2f(d.y);
            const f32x2 one = {1.f, 1.f};
            const f32x2 tpe = e + one;                                // v_pk_add
            f32x2 s;
            s.x = __builtin_amdgcn_logf(tpe.x);                       // trans x2
            s.y = __builtin_amdgcn_logf(tpe.y);
            Ra = Ra + s;                                              // v_pk_add
#pragma unroll
            for (int g = 0; g < NG; ++g) {
                const float bg = ((mj >> g) & 1) ? 1.f : 0.f;          // SGPR select
                const f32x2 bgv = {bg, bg};
                Rg[g] = __builtin_elementwise_fma(bgv, s, Rg[g]);      // v_pk_fma
            }
        }
    }
    if (prev_bi >= 0) flush();
    if (tid < 27) part[tid * NBLK + blk] = acc[tid];   // zeros when no tiles
}

// ---------------------------------------------------------------------------
// Dispatch 3: reduce 27 x NBLK partials (x ln2) + integer counts + fp64 tail.
// (Proven in R6 verbatim.)
// ---------------------------------------------------------------------------
__global__ __launch_bounds__(512) void k_final(
    const float* __restrict__ part, const int* __restrict__ cntT,
    const int* __restrict__ cntN, const int* __restrict__ gTc,
    const int* __restrict__ gNc, int B, float* __restrict__ out) {

    __shared__ float fin[27];
    __shared__ int cTs[NG], cNs[NG], nTs, nNs;
    const int tid = threadIdx.x, lane = tid & 63, wave = tid >> 6;
    const int nCh = (B + CHROWS - 1) / CHROWS;

    for (int r = wave; r < 27; r += 8) {
        float s = 0.f;
#pragma unroll
        for (int q = 0; q < NBLK / 64; ++q) s += part[r * NBLK + (q << 6) + lane];
#pragma unroll
        for (int off = 32; off > 0; off >>= 1) s += __shfl_xor(s, off, 64);
        if (lane == 0) fin[r] = s * LN2;     // undo log2-domain accumulation
    }
    if (tid < NG) {
        int s = 0;
        for (int c = 0; c < nCh; ++c) s += gTc[c * NG + tid];
        cTs[tid] = s;
    } else if (tid >= 64 && tid < 64 + NG) {
        const int g = tid - 64;
        int s = 0;
        for (int c = 0; c < nCh; ++c) s += gNc[c * NG + g];
        cNs[g] = s;
    } else if (tid == 128) {
        int s = 0;
        for (int c = 0; c < nCh; ++c) s += cntT[c];
        nTs = s;
    } else if (tid == 192) {
        int s = 0;
        for (int c = 0; c < nCh; ++c) s += cntN[c];
        nNs = s;
    }
    __syncthreads();
    if (tid == 0) {
        const long long nT64 = nTs, nN64 = nNs;
        double accd = 0.0; int ngv = 0;
        for (int g = 0; g < NG; ++g) {
            const long long cT = cTs[g], cN = cNs[g];
            const long long c0 = cT * cN;
            const long long c1 = (nT64 - cT) * cN;
            const long long c2 = cT * (nN64 - cN);
            const double t0 = (double)fin[g]          / (double)(c0 > 0 ? c0 : 1);
            const double t1 = (double)fin[NG + g]     / (double)(c1 > 0 ? c1 : 1);
            const double t2 = (double)fin[2 * NG + g] / (double)(c2 > 0 ? c2 : 1);
            const int nv = (c0 > 0) + (c1 > 0) + (c2 > 0);
            const double gl = ((c0 > 0 ? t0 : 0.0) + (c1 > 0 ? t1 : 0.0) +
                               (c2 > 0 ? t2 : 0.0)) / (double)(nv > 0 ? nv : 1);
            if (nv > 0) { const double g2 = gl * gl; accd += g2 * g2; ++ngv; }
        }
        const double mp = accd / (double)(ngv > 0 ? ngv : 1);
        const double loss = sqrt(sqrt(mp));   // ^(1/4)
        out[0] = (float)(ngv > 0 ? loss : 0.0);
    }
}

extern "C" void kernel_launch(void* const* d_in, const int* in_sizes, int n_in,
                              void* d_out, int out_size, void* d_ws, size_t ws_size,
                              hipStream_t stream) {
    const float* logits = (const float*)d_in[0];
    const float* ytox   = (const float*)d_in[1];
    const float* yid    = (const float*)d_in[2];
    const int B = in_sizes[0];
    const int nCh = (B + CHROWS - 1) / CHROWS;

    char* ws = (char*)d_ws;
    int* cntT = (int*)ws;                               // NCHMAX
    int* cntN = cntT + NCHMAX;                          // NCHMAX
    int* gTc  = cntN + NCHMAX;                          // NCHMAX*NG
    int* gNc  = gTc + NCHMAX * NG;                      // NCHMAX*NG
    float2* iTmp = (float2*)(gNc + NCHMAX * NG);        // B float2 (8B aligned)
    float2* jTmp = iTmp + B;                            // B float2
    float*  part = (float*)(jTmp + B);                  // 27*NBLK floats

    k_classify<<<dim3(nCh), dim3(256), 0, stream>>>(
        logits, ytox, yid, B, cntT, cntN, gTc, gNc, iTmp, jTmp);
    k_pairs<<<dim3(NBLK), dim3(256), 0, stream>>>(cntT, cntN, iTmp, jTmp, B, part);
    k_final<<<dim3(1), dim3(512), 0, stream>>>(part, cntT, cntN, gTc, gNc, B,
                                               (float*)d_out);
}